// Round 11
// baseline (473.229 us; speedup 1.0000x reference)
//
#include <hip/hip_runtime.h>

#define N_GRID 144
#define INV_DX 128.0f
#define NBINS 32768          // 32 x 32 x 32 bins of 4^3 cells
#define SCAN_THREADS 1024
#define PER_THREAD 32        // 1024 * 32 = 32768
#define KP 8                 // particles per thread in streaming passes
#define PERSIST 2048         // co-resident blocks: 8/CU x 256 CU -> stable XCD pinning

__device__ __forceinline__ int bin_of(float px, float py, float pz) {
    int bx = (int)(px * INV_DX);   // 0..127
    int by = (int)(py * INV_DX);
    int bz = (int)(pz * INV_DX);
    return ((bx >> 2) << 10) | ((by >> 2) << 5) | (bz >> 2);
}

// Pass 0: bin16[i] = bin index (coalesced read/write, no atomics)
__global__ void __launch_bounds__(256) binify_kernel(
    const float* __restrict__ pos, unsigned short* __restrict__ bin16, int n)
{
    int base = blockIdx.x * (blockDim.x * KP) + threadIdx.x;
#pragma unroll
    for (int k = 0; k < KP; ++k) {
        int p = base + k * 256;
        if (p < n) {
            float px = pos[3 * p + 0];
            float py = pos[3 * p + 1];
            float pz = pos[3 * p + 2];
            bin16[p] = (unsigned short)bin_of(px, py, pz);
        }
    }
}

// Pass 1: persistent octant-pinned histogram. 2048 co-resident blocks; block
// (owner = blockIdx&7) stays on XCD owner for its lifetime (round-robin
// dispatch + co-residency), so atomics hit an XCD-private 16KB hist slice.
__global__ void __launch_bounds__(256) hist8_kernel(
    const unsigned short* __restrict__ bin16, unsigned int* __restrict__ hist,
    int n, int nchunks)
{
    int owner = blockIdx.x & 7;
    int stride = gridDim.x >> 3;
    for (int c = blockIdx.x >> 3; c < nchunks; c += stride) {
        int base = c * (256 * KP) + threadIdx.x;
        int bn[KP], ok[KP];
#pragma unroll
        for (int k = 0; k < KP; ++k) {
            int p = base + k * 256;
            ok[k] = (p < n);
            bn[k] = bin16[ok[k] ? p : 0];
            ok[k] = ok[k] && ((bn[k] >> 12) == owner);
        }
#pragma unroll
        for (int k = 0; k < KP; ++k) {
            if (ok[k]) atomicAdd(&hist[bn[k]], 1u);
        }
    }
}

__global__ void __launch_bounds__(SCAN_THREADS) scan_kernel(
    const unsigned int* __restrict__ hist, unsigned int* __restrict__ offs)
{
    __shared__ unsigned int partial[SCAN_THREADS];
    int t = threadIdx.x;
    unsigned int local[PER_THREAD];
    unsigned int s = 0;
    int base = t * PER_THREAD;
#pragma unroll
    for (int k = 0; k < PER_THREAD; ++k) {
        local[k] = s;
        s += hist[base + k];
    }
    partial[t] = s;
    __syncthreads();
    for (int d = 1; d < SCAN_THREADS; d <<= 1) {
        unsigned int v = (t >= d) ? partial[t - d] : 0u;
        __syncthreads();
        partial[t] += v;
        __syncthreads();
    }
    unsigned int chunk_excl = (t == 0) ? 0u : partial[t - 1];
#pragma unroll
    for (int k = 0; k < PER_THREAD; ++k)
        offs[base + k] = chunk_excl + local[k];
}

// Pass 2: persistent octant-pinned INDEX-ONLY scatter. Reads bin16 densely
// (64MB total, LLC-warm); writes 4B particle index per slot. All writers of
// any idxsorted line are pinned to one XCD -> partial stores merge in its L2.
__global__ void __launch_bounds__(256) scatter_idx8_kernel(
    const unsigned short* __restrict__ bin16, unsigned int* __restrict__ idxsorted,
    unsigned int* __restrict__ offs, int n, int nchunks)
{
    int owner = blockIdx.x & 7;
    int stride = gridDim.x >> 3;
    for (int c = blockIdx.x >> 3; c < nchunks; c += stride) {
        int base = c * (256 * KP) + threadIdx.x;
        int bn[KP], ok[KP];
#pragma unroll
        for (int k = 0; k < KP; ++k) {
            int p = base + k * 256;
            ok[k] = (p < n);
            bn[k] = bin16[ok[k] ? p : 0];
            ok[k] = ok[k] && ((bn[k] >> 12) == owner);
        }
        unsigned int off[KP];
#pragma unroll
        for (int k = 0; k < KP; ++k) {
            if (ok[k]) off[k] = atomicAdd(&offs[bn[k]], 1u);
        }
#pragma unroll
        for (int k = 0; k < KP; ++k) {
            if (ok[k]) idxsorted[off[k]] = (unsigned int)(base + k * 256);
        }
    }
}

// Pass 3: bin-centric gather. One 128-thread block per bin; 6x6x6-node
// stencil (648 floats) in LDS; per particle: coalesced idx read, random
// 12B pos read (LLC-resident), 27 LDS taps, random 12B out write.
__global__ void __launch_bounds__(128) gather_bin_kernel(
    const float* __restrict__ grid,
    const float* __restrict__ pos,
    const unsigned int* __restrict__ idxsorted,
    const unsigned int* __restrict__ offs_end,
    const unsigned int* __restrict__ hist,
    float* __restrict__ out)
{
    int b = (blockIdx.x & 7) * 4096 + (blockIdx.x >> 3);   // bijective, 32768=8*4096

    unsigned int end = offs_end[b];
    unsigned int cnt = hist[b];
    if (cnt == 0) return;
    unsigned int start = end - cnt;

    int obx = 4 * (b >> 10);
    int oby = 4 * ((b >> 5) & 31);
    int obz = 4 * (b & 31);

    const int s1 = N_GRID * 3;
    const int s0 = N_GRID * N_GRID * 3;

    __shared__ float R[648];          // [6][6][18]
    const float* gorig = grid + (long)obx * s0 + oby * s1 + obz * 3;
    int tid = threadIdx.x;
#pragma unroll
    for (int f = tid; f < 648; f += 128) {
        int row = f / 18;
        int zz = f - row * 18;
        R[f] = gorig[(row / 6) * s0 + (row % 6) * s1 + zz];
    }
    __syncthreads();

    for (unsigned int j = start + tid; j < end; j += 128) {
        unsigned int pidx = idxsorted[j];

        float px = pos[3 * pidx + 0];
        float py = pos[3 * pidx + 1];
        float pz = pos[3 * pidx + 2];

        float nx = px * INV_DX;
        float ny = py * INV_DX;
        float nz = pz * INV_DX;
        int bx = (int)nx;
        int by = (int)ny;
        int bz = (int)nz;
        float lx = nx - (float)bx;
        float ly = ny - (float)by;
        float lz = nz - (float)bz;

        float wx[3], wy[3], wz[3];
        wx[0] = 0.5f * (1.0f - lx) * (1.0f - lx);
        wx[1] = 0.75f - (0.5f - lx) * (0.5f - lx);
        wx[2] = 0.5f * lx * lx;
        wy[0] = 0.5f * (1.0f - ly) * (1.0f - ly);
        wy[1] = 0.75f - (0.5f - ly) * (0.5f - ly);
        wy[2] = 0.5f * ly * ly;
        wz[0] = 0.5f * (1.0f - lz) * (1.0f - lz);
        wz[1] = 0.75f - (0.5f - lz) * (0.5f - lz);
        wz[2] = 0.5f * lz * lz;

        int rx = bx - obx;
        int ry = by - oby;
        int rz = bz - obz;

        float ox = 0.0f, oy = 0.0f, oz = 0.0f;
#pragma unroll
        for (int a = 0; a < 3; ++a) {
#pragma unroll
            for (int bb = 0; bb < 3; ++bb) {
                const float* pp = &R[((rx + a) * 6 + (ry + bb)) * 18 + rz * 3];
                float wab = wx[a] * wy[bb];
                float w0 = wab * wz[0];
                float w1 = wab * wz[1];
                float w2 = wab * wz[2];
                ox += w0 * pp[0] + w1 * pp[3] + w2 * pp[6];
                oy += w0 * pp[1] + w1 * pp[4] + w2 * pp[7];
                oz += w0 * pp[2] + w1 * pp[5] + w2 * pp[8];
            }
        }

        out[3 * pidx + 0] = ox;
        out[3 * pidx + 1] = oy;
        out[3 * pidx + 2] = oz;
    }
}

// Fallback: naive per-particle gather
__global__ void __launch_bounds__(256) g2p_naive_kernel(
    const float* __restrict__ grid, const float* __restrict__ pos,
    float* __restrict__ out, int n)
{
    int i = blockIdx.x * blockDim.x + threadIdx.x;
    if (i >= n) return;
    float px = pos[3 * i + 0], py = pos[3 * i + 1], pz = pos[3 * i + 2];
    float nx = px * INV_DX, ny = py * INV_DX, nz = pz * INV_DX;
    int bx = (int)nx, by = (int)ny, bz = (int)nz;
    float lx = nx - bx, ly = ny - by, lz = nz - bz;
    float wx[3], wy[3], wz[3];
    wx[0] = 0.5f * (1.0f - lx) * (1.0f - lx);
    wx[1] = 0.75f - (0.5f - lx) * (0.5f - lx);
    wx[2] = 0.5f * lx * lx;
    wy[0] = 0.5f * (1.0f - ly) * (1.0f - ly);
    wy[1] = 0.75f - (0.5f - ly) * (0.5f - ly);
    wy[2] = 0.5f * ly * ly;
    wz[0] = 0.5f * (1.0f - lz) * (1.0f - lz);
    wz[1] = 0.75f - (0.5f - lz) * (0.5f - lz);
    wz[2] = 0.5f * lz * lz;
    const int s1 = N_GRID * 3, s0 = N_GRID * N_GRID * 3;
    const float* gbase = grid + (long)bx * s0 + by * s1 + bz * 3;
    float ox = 0, oy = 0, oz = 0;
#pragma unroll
    for (int a = 0; a < 3; ++a)
#pragma unroll
        for (int b = 0; b < 3; ++b) {
            const float* pp = gbase + a * s0 + b * s1;
            float wab = wx[a] * wy[b];
            float w0 = wab * wz[0], w1 = wab * wz[1], w2 = wab * wz[2];
            ox += w0 * pp[0] + w1 * pp[3] + w2 * pp[6];
            oy += w0 * pp[1] + w1 * pp[4] + w2 * pp[7];
            oz += w0 * pp[2] + w1 * pp[5] + w2 * pp[8];
        }
    out[3 * i + 0] = ox;
    out[3 * i + 1] = oy;
    out[3 * i + 2] = oz;
}

extern "C" void kernel_launch(void* const* d_in, const int* in_sizes, int n_in,
                              void* d_out, int out_size, void* d_ws, size_t ws_size,
                              hipStream_t stream) {
    const float* grid = (const float*)d_in[0];
    const float* pos  = (const float*)d_in[1];
    float* out        = (float*)d_out;
    int n = in_sizes[1] / 3;

    int block = 256;
    int blocks = (n + block - 1) / block;
    int nchunks = (n + block * KP - 1) / (block * KP);

    // ws layout: [0,128K) hist | [128K,256K) offs | [256K, 256K+2n) bin16 |
    //            [align256, +4n) idxsorted
    size_t bin_off = 256u << 10;
    size_t idx_off = (bin_off + (size_t)n * 2 + 255) & ~(size_t)255;
    size_t need = idx_off + (size_t)n * sizeof(unsigned int);

    if (ws_size < need) {
        g2p_naive_kernel<<<blocks, block, 0, stream>>>(grid, pos, out, n);
        return;
    }

    unsigned int* hist = (unsigned int*)d_ws;
    unsigned int* offs = hist + NBINS;
    unsigned short* bin16 = (unsigned short*)((char*)d_ws + bin_off);
    unsigned int* idxsorted = (unsigned int*)((char*)d_ws + idx_off);

    hipMemsetAsync(hist, 0, NBINS * sizeof(unsigned int), stream);
    binify_kernel<<<nchunks, block, 0, stream>>>(pos, bin16, n);
    hist8_kernel<<<PERSIST, block, 0, stream>>>(bin16, hist, n, nchunks);
    scan_kernel<<<1, SCAN_THREADS, 0, stream>>>(hist, offs);
    scatter_idx8_kernel<<<PERSIST, block, 0, stream>>>(bin16, idxsorted, offs, n, nchunks);
    gather_bin_kernel<<<NBINS, 128, 0, stream>>>(grid, pos, idxsorted, offs, hist, out);
}

// Round 12
// 404.002 us; speedup vs baseline: 1.1714x; 1.1714x over previous
//
#include <hip/hip_runtime.h>

#define N_GRID 144
#define INV_DX 128.0f
#define NBINS 32768          // 32 x 32 x 32 bins of 4^3 cells
#define SCAN_THREADS 1024
#define PER_THREAD 32        // 1024 * 32 = 32768
#define KP 8                 // particles per thread in streaming passes

__device__ __forceinline__ int bin_of(float px, float py, float pz) {
    int bx = (int)(px * INV_DX);   // 0..127
    int by = (int)(py * INV_DX);
    int bz = (int)(pz * INV_DX);
    return ((bx >> 2) << 10) | ((by >> 2) << 5) | (bz >> 2);
}

// Pass 0: bin16[i] = bin index (coalesced, no atomics). Feeds hist8 only.
__global__ void __launch_bounds__(256) binify_kernel(
    const float* __restrict__ pos, unsigned short* __restrict__ bin16, int n)
{
    int base = blockIdx.x * (blockDim.x * KP) + threadIdx.x;
#pragma unroll
    for (int k = 0; k < KP; ++k) {
        int p = base + k * 256;
        if (p < n) {
            float px = pos[3 * p + 0];
            float py = pos[3 * p + 1];
            float pz = pos[3 * p + 2];
            bin16[p] = (unsigned short)bin_of(px, py, pz);
        }
    }
}

// Pass 1: octant-filtered histogram from bin16 (2B/particle stream, 8x).
// Atomics hit an XCD-private 16KB hist slice (bin>>12 = x-octant).
__global__ void __launch_bounds__(256) hist8_kernel(
    const unsigned short* __restrict__ bin16, unsigned int* __restrict__ hist, int n)
{
    int owner = blockIdx.x & 7;
    int chunk = blockIdx.x >> 3;
    int base = chunk * (256 * KP) + threadIdx.x;
    int bn[KP], ok[KP];
#pragma unroll
    for (int k = 0; k < KP; ++k) {
        int p = base + k * 256;
        ok[k] = (p < n);
        bn[k] = bin16[ok[k] ? p : 0];
        ok[k] = ok[k] && ((bn[k] >> 12) == owner);
    }
#pragma unroll
    for (int k = 0; k < KP; ++k) {
        if (ok[k]) atomicAdd(&hist[bn[k]], 1u);
    }
}

__global__ void __launch_bounds__(SCAN_THREADS) scan_kernel(
    const unsigned int* __restrict__ hist, unsigned int* __restrict__ offs)
{
    __shared__ unsigned int partial[SCAN_THREADS];
    int t = threadIdx.x;
    unsigned int local[PER_THREAD];
    unsigned int s = 0;
    int base = t * PER_THREAD;
#pragma unroll
    for (int k = 0; k < PER_THREAD; ++k) {
        local[k] = s;
        s += hist[base + k];
    }
    partial[t] = s;
    __syncthreads();
    for (int d = 1; d < SCAN_THREADS; d <<= 1) {
        unsigned int v = (t >= d) ? partial[t - d] : 0u;
        __syncthreads();
        partial[t] += v;
        __syncthreads();
    }
    unsigned int chunk_excl = (t == 0) ? 0u : partial[t - 1];
#pragma unroll
    for (int k = 0; k < PER_THREAD; ++k)
        offs[base + k] = chunk_excl + local[k];
}

// Pass 2: R5-style scatter — dense coalesced pos reads, bin computed INLINE
// (no bin16 stream), octant filter for XCD-local atomics + same-XCD
// sorted-line writers, float4(pos,pidx) payload.
__global__ void __launch_bounds__(256) scatter8_kernel(
    const float* __restrict__ pos, float4* __restrict__ sorted,
    unsigned int* __restrict__ offs, int n)
{
    int owner = blockIdx.x & 7;
    int chunk = blockIdx.x >> 3;
    int base = chunk * (256 * KP) + threadIdx.x;
    float px[KP], py[KP], pz[KP];
    int ok[KP], bn[KP];
#pragma unroll
    for (int k = 0; k < KP; ++k) {
        int p = base + k * 256;
        ok[k] = (p < n);
        int q = ok[k] ? p : 0;
        px[k] = pos[3 * q + 0];
        py[k] = pos[3 * q + 1];
        pz[k] = pos[3 * q + 2];
    }
#pragma unroll
    for (int k = 0; k < KP; ++k) {
        bn[k] = bin_of(px[k], py[k], pz[k]);
        ok[k] = ok[k] && ((bn[k] >> 12) == owner);
    }
    unsigned int off[KP];
#pragma unroll
    for (int k = 0; k < KP; ++k) {
        if (ok[k]) off[k] = atomicAdd(&offs[bn[k]], 1u);
    }
#pragma unroll
    for (int k = 0; k < KP; ++k) {
        if (ok[k]) {
            float4 v;
            v.x = px[k]; v.y = py[k]; v.z = pz[k];
            v.w = __int_as_float(base + k * 256);
            sorted[off[k]] = v;
        }
    }
}

// Pass 3: bin-centric gather. One 128-thread block per bin; 6x6x6-node
// stencil (648 floats, 2.6KB) staged to LDS; 27 taps from LDS. Octant-
// swizzled so each XCD reads a ~4.5MB grid x-slab (L2-fit).
__global__ void __launch_bounds__(128) gather_bin_kernel(
    const float* __restrict__ grid,
    const float4* __restrict__ sorted,
    const unsigned int* __restrict__ offs_end,
    const unsigned int* __restrict__ hist,
    float* __restrict__ out)
{
    int b = (blockIdx.x & 7) * 4096 + (blockIdx.x >> 3);   // bijective, 32768=8*4096

    unsigned int end = offs_end[b];
    unsigned int cnt = hist[b];
    if (cnt == 0) return;
    unsigned int start = end - cnt;

    int obx = 4 * (b >> 10);
    int oby = 4 * ((b >> 5) & 31);
    int obz = 4 * (b & 31);

    const int s1 = N_GRID * 3;
    const int s0 = N_GRID * N_GRID * 3;

    __shared__ float R[648];          // [6][6][18]
    const float* gorig = grid + (long)obx * s0 + oby * s1 + obz * 3;
    int tid = threadIdx.x;
#pragma unroll
    for (int f = tid; f < 648; f += 128) {
        int row = f / 18;
        int zz = f - row * 18;
        R[f] = gorig[(row / 6) * s0 + (row % 6) * s1 + zz];
    }
    __syncthreads();

    for (unsigned int j = start + tid; j < end; j += 128) {
        float4 p = sorted[j];
        int idx = __float_as_int(p.w);

        float nx = p.x * INV_DX;
        float ny = p.y * INV_DX;
        float nz = p.z * INV_DX;
        int bx = (int)nx;
        int by = (int)ny;
        int bz = (int)nz;
        float lx = nx - (float)bx;
        float ly = ny - (float)by;
        float lz = nz - (float)bz;

        float wx[3], wy[3], wz[3];
        wx[0] = 0.5f * (1.0f - lx) * (1.0f - lx);
        wx[1] = 0.75f - (0.5f - lx) * (0.5f - lx);
        wx[2] = 0.5f * lx * lx;
        wy[0] = 0.5f * (1.0f - ly) * (1.0f - ly);
        wy[1] = 0.75f - (0.5f - ly) * (0.5f - ly);
        wy[2] = 0.5f * ly * ly;
        wz[0] = 0.5f * (1.0f - lz) * (1.0f - lz);
        wz[1] = 0.75f - (0.5f - lz) * (0.5f - lz);
        wz[2] = 0.5f * lz * lz;

        int rx = bx - obx;
        int ry = by - oby;
        int rz = bz - obz;

        float ox = 0.0f, oy = 0.0f, oz = 0.0f;
#pragma unroll
        for (int a = 0; a < 3; ++a) {
#pragma unroll
            for (int bb = 0; bb < 3; ++bb) {
                const float* pp = &R[((rx + a) * 6 + (ry + bb)) * 18 + rz * 3];
                float wab = wx[a] * wy[bb];
                float w0 = wab * wz[0];
                float w1 = wab * wz[1];
                float w2 = wab * wz[2];
                ox += w0 * pp[0] + w1 * pp[3] + w2 * pp[6];
                oy += w0 * pp[1] + w1 * pp[4] + w2 * pp[7];
                oz += w0 * pp[2] + w1 * pp[5] + w2 * pp[8];
            }
        }

        out[3 * idx + 0] = ox;
        out[3 * idx + 1] = oy;
        out[3 * idx + 2] = oz;
    }
}

// Fallback: naive per-particle gather
__global__ void __launch_bounds__(256) g2p_naive_kernel(
    const float* __restrict__ grid, const float* __restrict__ pos,
    float* __restrict__ out, int n)
{
    int i = blockIdx.x * blockDim.x + threadIdx.x;
    if (i >= n) return;
    float px = pos[3 * i + 0], py = pos[3 * i + 1], pz = pos[3 * i + 2];
    float nx = px * INV_DX, ny = py * INV_DX, nz = pz * INV_DX;
    int bx = (int)nx, by = (int)ny, bz = (int)nz;
    float lx = nx - bx, ly = ny - by, lz = nz - bz;
    float wx[3], wy[3], wz[3];
    wx[0] = 0.5f * (1.0f - lx) * (1.0f - lx);
    wx[1] = 0.75f - (0.5f - lx) * (0.5f - lx);
    wx[2] = 0.5f * lx * lx;
    wy[0] = 0.5f * (1.0f - ly) * (1.0f - ly);
    wy[1] = 0.75f - (0.5f - ly) * (0.5f - ly);
    wy[2] = 0.5f * ly * ly;
    wz[0] = 0.5f * (1.0f - lz) * (1.0f - lz);
    wz[1] = 0.75f - (0.5f - lz) * (0.5f - lz);
    wz[2] = 0.5f * lz * lz;
    const int s1 = N_GRID * 3, s0 = N_GRID * N_GRID * 3;
    const float* gbase = grid + (long)bx * s0 + by * s1 + bz * 3;
    float ox = 0, oy = 0, oz = 0;
#pragma unroll
    for (int a = 0; a < 3; ++a)
#pragma unroll
        for (int b = 0; b < 3; ++b) {
            const float* pp = gbase + a * s0 + b * s1;
            float wab = wx[a] * wy[b];
            float w0 = wab * wz[0], w1 = wab * wz[1], w2 = wab * wz[2];
            ox += w0 * pp[0] + w1 * pp[3] + w2 * pp[6];
            oy += w0 * pp[1] + w1 * pp[4] + w2 * pp[7];
            oz += w0 * pp[2] + w1 * pp[5] + w2 * pp[8];
        }
    out[3 * i + 0] = ox;
    out[3 * i + 1] = oy;
    out[3 * i + 2] = oz;
}

extern "C" void kernel_launch(void* const* d_in, const int* in_sizes, int n_in,
                              void* d_out, int out_size, void* d_ws, size_t ws_size,
                              hipStream_t stream) {
    const float* grid = (const float*)d_in[0];
    const float* pos  = (const float*)d_in[1];
    float* out        = (float*)d_out;
    int n = in_sizes[1] / 3;

    int block = 256;
    int blocks = (n + block - 1) / block;
    int blocksK = (n + block * KP - 1) / (block * KP);

    // ws layout: [0,128K) hist | [128K,256K) offs | [256K, 256K+2n) bin16 |
    //            [align256, +16n) sorted
    size_t bin_off = 256u << 10;
    size_t sorted_off = (bin_off + (size_t)n * 2 + 255) & ~(size_t)255;
    size_t need = sorted_off + (size_t)n * sizeof(float4);

    if (ws_size < need) {
        g2p_naive_kernel<<<blocks, block, 0, stream>>>(grid, pos, out, n);
        return;
    }

    unsigned int* hist = (unsigned int*)d_ws;
    unsigned int* offs = hist + NBINS;
    unsigned short* bin16 = (unsigned short*)((char*)d_ws + bin_off);
    float4* sorted = (float4*)((char*)d_ws + sorted_off);

    hipMemsetAsync(hist, 0, NBINS * sizeof(unsigned int), stream);
    binify_kernel<<<blocksK, block, 0, stream>>>(pos, bin16, n);
    hist8_kernel<<<blocksK * 8, block, 0, stream>>>(bin16, hist, n);
    scan_kernel<<<1, SCAN_THREADS, 0, stream>>>(hist, offs);
    scatter8_kernel<<<blocksK * 8, block, 0, stream>>>(pos, sorted, offs, n);
    gather_bin_kernel<<<NBINS, 128, 0, stream>>>(grid, sorted, offs, hist, out);
}